// Round 2
// 572.580 us; speedup vs baseline: 1.0613x; 1.0613x over previous
//
#include <hip/hip_runtime.h>
#include <stdint.h>
#include <stddef.h>

#define HD 512
#define NP 11
#define PT 200
#define PSTRIDE 180
#define OL 2000
#define NC 8
#define NB 1024

typedef __bf16 bf16x8 __attribute__((ext_vector_type(8)));
typedef float floatx4 __attribute__((ext_vector_type(4)));

__device__ __forceinline__ unsigned short f2bf(float f) {
    unsigned int u = __float_as_uint(f);
    u = u + 0x7FFFu + ((u >> 16) & 1u);
    return (unsigned short)(u >> 16);
}
__device__ __forceinline__ float bf2f(unsigned short s) {
    return __uint_as_float(((unsigned int)s) << 16);
}
__device__ __forceinline__ float gelu_erf(float x) {
    return 0.5f * x * (1.0f + erff(x * 0.70710678118654752440f));
}
// async global->LDS, 16B per lane; lptr must be wave-uniform (HW: base + lane*16)
__device__ __forceinline__ void async16(const unsigned short* g, unsigned short* l) {
    __builtin_amdgcn_global_load_lds(
        (const __attribute__((address_space(1))) unsigned int*)g,
        (__attribute__((address_space(3))) unsigned int*)l, 16, 0, 0);
}

// ---------------- cast X fp32 -> bf16 ------------------------------------
__global__ __launch_bounds__(256) void cast_x_kernel(const float* __restrict__ x,
                                                     unsigned short* __restrict__ xb) {
    int idx = blockIdx.x * 256 + threadIdx.x;
    float4 v = ((const float4*)x)[idx];
    ushort4 o;
    o.x = f2bf(v.x); o.y = f2bf(v.y); o.z = f2bf(v.z); o.w = f2bf(v.w);
    ((ushort4*)xb)[idx] = o;
}

// ---------------- GEMM weight prep ---------------------------------------
__global__ __launch_bounds__(256) void prep_w_kernel(const float* __restrict__ W1,
                                                     const float* __restrict__ W2,
                                                     unsigned short* __restrict__ W1t,
                                                     unsigned short* __restrict__ W2t) {
    int idx = blockIdx.x * 256 + threadIdx.x;
    if (idx < 512 * 512) {
        int n = idx >> 9, k = idx & 511;
        W1t[idx] = f2bf(W1[k * 512 + n]);
    } else {
        int j = idx - 512 * 512;
        int n = j >> 9, k = j & 511;
        W2t[j] = (n < PT) ? f2bf(W2[k * PT + n]) : (unsigned short)0;
    }
}

// ---------------- conv weight prep (A-fragment order, bf16) ---------------
__global__ __launch_bounds__(256) void prep_cw_kernel(const float* __restrict__ rw1,
                                                      const float* __restrict__ rw2,
                                                      const float* __restrict__ rw3,
                                                      unsigned short* __restrict__ Wt1,
                                                      unsigned short* __restrict__ Wt2,
                                                      unsigned short* __restrict__ Wt3) {
    int idx = blockIdx.x * 256 + threadIdx.x;   // 15872 exact (62 blocks)
    if (idx < 4096) {
        int kb = idx >> 10, rem = idx & 1023, oc = rem >> 5, k = rem & 31;
        int tl = k >> 3, ic = k & 7, tap = kb * 4 + tl;
        Wt1[idx] = (tap < 15) ? f2bf(rw1[(oc * 8 + ic) * 15 + tap]) : (unsigned short)0;
    } else if (idx < 4096 + 7680) {
        int j = idx - 4096;
        int t = j >> 9, rem = j & 511, oc = rem >> 5, ic = rem & 31;
        Wt2[j] = f2bf(rw2[(oc * 32 + ic) * 15 + t]);
    } else {
        int j = idx - 11776;   // < 4096
        int kb = j >> 9, rem = j & 511, m = rem >> 5, k = rem & 31;
        int tl = k >> 4, ic = k & 15, tap = kb * 2 + tl;
        Wt3[j] = (m < 8 && tap < 15) ? f2bf(rw3[(m * 16 + ic) * 15 + tap]) : (unsigned short)0;
    }
}

// ---------------- bf16 MFMA GEMM, global_load_lds staging -----------------
// A: M x 512 bf16 row-major. Bt: N x 512 bf16. 128x128 tile, BK=32.
template<bool FUSE_GELU, bool OUT_BF16, int LOG2_NT>
__global__ __launch_bounds__(256) void gemm_lds_kernel(const unsigned short* __restrict__ A,
                                                       const unsigned short* __restrict__ Bt,
                                                       const float* __restrict__ bias,
                                                       void* __restrict__ Cout,
                                                       int out_stride, int n_valid) {
    __shared__ __align__(16) unsigned short As[128 * 32];
    __shared__ __align__(16) unsigned short Bs[128 * 32];
    const int tid  = threadIdx.x;
    const int lane = tid & 63;
    const int wid  = tid >> 6;
    const int bid  = blockIdx.x;
    const int nt   = (bid >> 3) & ((1 << LOG2_NT) - 1);
    const int mt   = (bid >> (3 + LOG2_NT)) * 8 + (bid & 7);
    const int m0 = mt * 128;
    const int n0 = nt * 128;
    const int mw = (wid >> 1) * 64;
    const int nw = (wid & 1) * 64;
    const int l15  = lane & 15;
    const int quad = lane >> 4;
    const int srow = lane >> 2;        // 0..15 within a 16-row chunk
    const int scol = (lane & 3) * 8;   // k-offset in shorts

    floatx4 acc[4][4];
#pragma unroll
    for (int i = 0; i < 4; ++i)
#pragma unroll
        for (int j = 0; j < 4; ++j) acc[i][j] = (floatx4)0.0f;

    for (int k0 = 0; k0 < 512; k0 += 32) {
#pragma unroll
        for (int p = 0; p < 2; ++p) {
            const int rbase = wid * 32 + p * 16;
            async16(A  + (size_t)(m0 + rbase + srow) * 512 + k0 + scol, As + rbase * 32);
            async16(Bt + (size_t)(n0 + rbase + srow) * 512 + k0 + scol, Bs + rbase * 32);
        }
        __syncthreads();
        bf16x8 af[4], bfr[4];
#pragma unroll
        for (int t = 0; t < 4; ++t) {
            af[t]  = *(const bf16x8*)(As + (mw + t * 16 + l15) * 32 + quad * 8);
            bfr[t] = *(const bf16x8*)(Bs + (nw + t * 16 + l15) * 32 + quad * 8);
        }
#pragma unroll
        for (int mtl = 0; mtl < 4; ++mtl)
#pragma unroll
            for (int ntl = 0; ntl < 4; ++ntl)
                acc[mtl][ntl] = __builtin_amdgcn_mfma_f32_16x16x32_bf16(af[mtl], bfr[ntl], acc[mtl][ntl], 0, 0, 0);
        __syncthreads();
    }

#pragma unroll
    for (int mtl = 0; mtl < 4; ++mtl) {
#pragma unroll
        for (int ntl = 0; ntl < 4; ++ntl) {
            const int col  = n0 + nw + ntl * 16 + l15;
            const int rowb = m0 + mw + mtl * 16 + quad * 4;
            const bool colok = (col < n_valid);
            float bv = colok ? bias[col] : 0.0f;
#pragma unroll
            for (int r = 0; r < 4; ++r) {
                float v = acc[mtl][ntl][r] + bv;
                if (FUSE_GELU) v = gelu_erf(v);
                if (colok) {
                    size_t off = (size_t)(rowb + r) * out_stride + col;
                    if (OUT_BF16) ((unsigned short*)Cout)[off] = f2bf(v);
                    else          ((float*)Cout)[off] = v;
                }
            }
        }
    }
}

// ---------------- fused tail: oadd + conv1 + conv2 + conv3 + res + pw -----
// One block = 256 output positions of one batch row. The full rec/c1/c2
// chain lives in LDS with a 21-position halo; only pat is read and only
// out is written to HBM.
__global__ __launch_bounds__(256) void tail_fused(const unsigned short* __restrict__ pat,
                                                  const unsigned short* __restrict__ Wt1,
                                                  const float* __restrict__ rb1,
                                                  const unsigned short* __restrict__ Wt2,
                                                  const float* __restrict__ rb2,
                                                  const unsigned short* __restrict__ Wt3,
                                                  const float* __restrict__ rb3,
                                                  const float* __restrict__ pw,
                                                  const float* __restrict__ pb,
                                                  float* __restrict__ out) {
    __shared__ __align__(16) unsigned short xs[304 * 8];    // rec bf16, row0 = seg0-21
    __shared__ __align__(16) unsigned short ys1[288 * 40];  // c1 tile,  row0 = seg0-14
    __shared__ __align__(16) unsigned short ys2[272 * 24];  // c2 tile,  row0 = seg0-7
    __shared__ __align__(16) float r2[256 * 12];            // rec fp32, central 256
    __shared__ float pws[64], bs1[32], bs2[16], bs3[8], bsp[8];
    const int tid = threadIdx.x;
    const int b = blockIdx.y;
    const int seg0 = blockIdx.x * 256;
    const int lane = tid & 63, wid = tid >> 6;
    const int l15 = lane & 15, quad = lane >> 4;

    if (tid < 64) pws[tid] = pw[tid];
    else if (tid < 96)  bs1[tid - 64]  = rb1[tid - 64];
    else if (tid < 112) bs2[tid - 96]  = rb2[tid - 96];
    else if (tid < 120) bs3[tid - 112] = rb3[tid - 112];
    else if (tid < 128) bsp[tid - 120] = pb[tid - 120];

    // ---- stage A: overlap-add -> xs (bf16, 304 rows) + r2 (fp32, 256) ----
    for (int row = tid; row < 304; row += 256) {
        int p = seg0 - 21 + row;
        float acc[8];
#pragma unroll
        for (int c = 0; c < 8; ++c) acc[c] = 0.0f;
        if (p >= 0 && p < OL) {
            int imin = (p >= PT) ? (p - (PT - PSTRIDE)) / PSTRIDE : 0;
            int imax = p / PSTRIDE; if (imax > NP - 1) imax = NP - 1;
            float wsum = 0.0f;
            for (int i = imin; i <= imax; ++i) {
                int t = p - i * PSTRIDE;
                float w = (t < 50) ? t * (1.0f / 49.0f)
                                   : ((t >= 150) ? (199 - t) * (1.0f / 49.0f) : 1.0f);
                wsum += w;
                const unsigned short* pp = pat + ((size_t)(b * NP + i) * NC) * PT + t;
#pragma unroll
                for (int c = 0; c < 8; ++c) acc[c] += bf2f(pp[c * PT]) * w;
            }
            float inv = 1.0f / fmaxf(wsum, 1e-8f);
#pragma unroll
            for (int c = 0; c < 8; ++c) acc[c] *= inv;
        }
        ushort4 o0, o1;
        o0.x = f2bf(acc[0]); o0.y = f2bf(acc[1]); o0.z = f2bf(acc[2]); o0.w = f2bf(acc[3]);
        o1.x = f2bf(acc[4]); o1.y = f2bf(acc[5]); o1.z = f2bf(acc[6]); o1.w = f2bf(acc[7]);
        *(ushort4*)(xs + row * 8)     = o0;
        *(ushort4*)(xs + row * 8 + 4) = o1;
        int cr = row - 21;
        if (cr >= 0 && cr < 256) {
            float4 v0 = { acc[0], acc[1], acc[2], acc[3] };
            float4 v1 = { acc[4], acc[5], acc[6], acc[7] };
            *(float4*)(r2 + cr * 12)     = v0;
            *(float4*)(r2 + cr * 12 + 4) = v1;
        }
    }
    __syncthreads();

    // ---- conv1: 8 -> 32, k15, gelu -> ys1 (288 positions) ----
    {
        bf16x8 wf[4][2];
#pragma unroll
        for (int kb = 0; kb < 4; ++kb)
#pragma unroll
            for (int ot = 0; ot < 2; ++ot)
                wf[kb][ot] = *(const bf16x8*)(Wt1 + (kb * 32 + ot * 16 + l15) * 32 + quad * 8);
#pragma unroll
        for (int u = 0; u < 5; ++u) {
            const int base = wid * 80 + u * 16;
            if (base < 288) {
                const int posl = base + l15;
                floatx4 a0 = (floatx4)0.0f, a1 = (floatx4)0.0f;
#pragma unroll
                for (int kb = 0; kb < 4; ++kb) {
                    int row = posl + kb * 4 + quad;
                    bf16x8 bfrag = *(const bf16x8*)(xs + row * 8);
                    a0 = __builtin_amdgcn_mfma_f32_16x16x32_bf16(wf[kb][0], bfrag, a0, 0, 0, 0);
                    a1 = __builtin_amdgcn_mfma_f32_16x16x32_bf16(wf[kb][1], bfrag, a1, 0, 0, 0);
                }
                int oc0 = quad * 4;
                ushort4 o;
                o.x = f2bf(gelu_erf(a0[0] + bs1[oc0]));
                o.y = f2bf(gelu_erf(a0[1] + bs1[oc0 + 1]));
                o.z = f2bf(gelu_erf(a0[2] + bs1[oc0 + 2]));
                o.w = f2bf(gelu_erf(a0[3] + bs1[oc0 + 3]));
                *(ushort4*)(ys1 + posl * 40 + oc0) = o;
                int oc1 = 16 + quad * 4;
                o.x = f2bf(gelu_erf(a1[0] + bs1[oc1]));
                o.y = f2bf(gelu_erf(a1[1] + bs1[oc1 + 1]));
                o.z = f2bf(gelu_erf(a1[2] + bs1[oc1 + 2]));
                o.w = f2bf(gelu_erf(a1[3] + bs1[oc1 + 3]));
                *(ushort4*)(ys1 + posl * 40 + oc1) = o;
            }
        }
    }
    __syncthreads();

    // ---- conv2: 32 -> 16, k15, gelu -> ys2 (272 positions) ----
    {
        bf16x8 wf[15];
#pragma unroll
        for (int t = 0; t < 15; ++t)
            wf[t] = *(const bf16x8*)(Wt2 + (t * 16 + l15) * 32 + quad * 8);
#pragma unroll
        for (int u = 0; u < 5; ++u) {
            const int base = wid * 80 + u * 16;
            if (base < 272) {
                const int posl = base + l15;
                floatx4 a = (floatx4)0.0f;
#pragma unroll
                for (int t = 0; t < 15; ++t) {
                    bf16x8 bfrag = *(const bf16x8*)(ys1 + (posl + t) * 40 + quad * 8);
                    a = __builtin_amdgcn_mfma_f32_16x16x32_bf16(wf[t], bfrag, a, 0, 0, 0);
                }
                int oc0 = quad * 4;
                ushort4 o;
                o.x = f2bf(gelu_erf(a[0] + bs2[oc0]));
                o.y = f2bf(gelu_erf(a[1] + bs2[oc0 + 1]));
                o.z = f2bf(gelu_erf(a[2] + bs2[oc0 + 2]));
                o.w = f2bf(gelu_erf(a[3] + bs2[oc0 + 3]));
                *(ushort4*)(ys2 + posl * 24 + oc0) = o;
            }
        }
    }
    __syncthreads();

    // ---- conv3: 16 -> 8, k15, + residual (into r2) ----
    {
        bf16x8 wf[8];
#pragma unroll
        for (int kb = 0; kb < 8; ++kb)
            wf[kb] = *(const bf16x8*)(Wt3 + (kb * 16 + l15) * 32 + quad * 8);
#pragma unroll
        for (int u = 0; u < 5; ++u) {
            const int base = wid * 80 + u * 16;
            if (base < 256) {
                const int posl = base + l15;
                floatx4 a = (floatx4)0.0f;
#pragma unroll
                for (int kb = 0; kb < 8; ++kb) {
                    int row = posl + kb * 2 + (quad >> 1);
                    bf16x8 bfrag = *(const bf16x8*)(ys2 + row * 24 + (quad & 1) * 8);
                    a = __builtin_amdgcn_mfma_f32_16x16x32_bf16(wf[kb], bfrag, a, 0, 0, 0);
                }
                if (quad < 2) {
                    int oc0 = quad * 4;
                    float4 rv = *(const float4*)(r2 + posl * 12 + oc0);
                    rv.x += a[0] + bs3[oc0];
                    rv.y += a[1] + bs3[oc0 + 1];
                    rv.z += a[2] + bs3[oc0 + 2];
                    rv.w += a[3] + bs3[oc0 + 3];
                    *(float4*)(r2 + posl * 12 + oc0) = rv;
                }
            }
        }
    }
    __syncthreads();

    // ---- pointwise 8x8 + store ----
    {
        int p = seg0 + tid;
        if (p < OL) {
            float4 a = *(const float4*)(r2 + tid * 12);
            float4 c = *(const float4*)(r2 + tid * 12 + 4);
#pragma unroll
            for (int o = 0; o < 8; ++o) {
                float v = bsp[o];
                v += pws[o * 8 + 0] * a.x + pws[o * 8 + 1] * a.y + pws[o * 8 + 2] * a.z + pws[o * 8 + 3] * a.w;
                v += pws[o * 8 + 4] * c.x + pws[o * 8 + 5] * c.y + pws[o * 8 + 6] * c.z + pws[o * 8 + 7] * c.w;
                out[((size_t)b * 8 + o) * OL + p] = v;
            }
        }
    }
}

// ---------------------------------------------------------------------------
extern "C" void kernel_launch(void* const* d_in, const int* in_sizes, int n_in,
                              void* d_out, int out_size, void* d_ws, size_t ws_size,
                              hipStream_t stream) {
    const float* X   = (const float*)d_in[0];
    const float* W1  = (const float*)d_in[1];
    const float* b1  = (const float*)d_in[2];
    const float* W2  = (const float*)d_in[3];
    const float* b2  = (const float*)d_in[4];
    const float* rw1 = (const float*)d_in[5];
    const float* rb1 = (const float*)d_in[6];
    const float* rw2 = (const float*)d_in[7];
    const float* rb2 = (const float*)d_in[8];
    const float* rw3 = (const float*)d_in[9];
    const float* rb3 = (const float*)d_in[10];
    const float* pw  = (const float*)d_in[11];
    const float* pb  = (const float*)d_in[12];
    float* out = (float*)d_out;

    char* ws = (char*)d_ws;
    unsigned short* Xb  = (unsigned short*)(ws);               //  92,274,688
    unsigned short* W1t = (unsigned short*)(ws +  92274688);   //     524,288
    unsigned short* W2t = (unsigned short*)(ws +  92798976);   //     262,144
    unsigned short* h   = (unsigned short*)(ws +  93061120);   //  92,274,688
    unsigned short* pat = (unsigned short*)(ws + 185335808);   //  36,044,800 (bf16 patches)
    unsigned short* Wt1 = (unsigned short*)(ws + 322961408);   //       8,192
    unsigned short* Wt2 = (unsigned short*)(ws + 322969600);   //      15,360
    unsigned short* Wt3 = (unsigned short*)(ws + 322984960);   //       8,192

    cast_x_kernel<<<45056, 256, 0, stream>>>(X, Xb);
    prep_w_kernel<<<1536, 256, 0, stream>>>(W1, W2, W1t, W2t);
    prep_cw_kernel<<<62, 256, 0, stream>>>(rw1, rw2, rw3, Wt1, Wt2, Wt3);
    gemm_lds_kernel<true,  true, 2><<<2816, 256, 0, stream>>>(Xb, W1t, b1, (void*)h,   512, 512);
    gemm_lds_kernel<false, true, 1><<<1408, 256, 0, stream>>>(h,  W2t, b2, (void*)pat, 200, 200);
    tail_fused<<<dim3(8, NB), 256, 0, stream>>>(pat, Wt1, rb1, Wt2, rb2, Wt3, rb3, pw, pb, out);
}

// Round 3
// 565.478 us; speedup vs baseline: 1.0746x; 1.0126x over previous
//
#include <hip/hip_runtime.h>
#include <stdint.h>
#include <stddef.h>

#define HD 512
#define NP 11
#define PT 200
#define PSTRIDE 180
#define OL 2000
#define NC 8
#define NB 1024

typedef __bf16 bf16x8 __attribute__((ext_vector_type(8)));
typedef float floatx4 __attribute__((ext_vector_type(4)));

// native RNE f32->bf16 (hardware v_cvt_pk_bf16_f32 when paired by compiler);
// bit-identical to the +0x7FFF rounding trick for finite values.
__device__ __forceinline__ unsigned short f2bf(float f) {
    return __builtin_bit_cast(unsigned short, (__bf16)f);
}
__device__ __forceinline__ float bf2f(unsigned short s) {
    return __uint_as_float(((unsigned int)s) << 16);
}
__device__ __forceinline__ float gelu_erf(float x) {
    return 0.5f * x * (1.0f + erff(x * 0.70710678118654752440f));
}
// async global->LDS, 16B per lane; lptr must be wave-uniform (HW: base + lane*16)
__device__ __forceinline__ void async16(const unsigned short* g, unsigned short* l) {
    __builtin_amdgcn_global_load_lds(
        (const __attribute__((address_space(1))) unsigned int*)g,
        (__attribute__((address_space(3))) unsigned int*)l, 16, 0, 0);
}

// ---------------- cast X fp32 -> bf16 ------------------------------------
__global__ __launch_bounds__(256) void cast_x_kernel(const float* __restrict__ x,
                                                     unsigned short* __restrict__ xb) {
    int idx = blockIdx.x * 256 + threadIdx.x;
    float4 v = ((const float4*)x)[idx];
    ushort4 o;
    o.x = f2bf(v.x); o.y = f2bf(v.y); o.z = f2bf(v.z); o.w = f2bf(v.w);
    ((ushort4*)xb)[idx] = o;
}

// ---------------- GEMM weight prep ---------------------------------------
__global__ __launch_bounds__(256) void prep_w_kernel(const float* __restrict__ W1,
                                                     const float* __restrict__ W2,
                                                     unsigned short* __restrict__ W1t,
                                                     unsigned short* __restrict__ W2t) {
    int idx = blockIdx.x * 256 + threadIdx.x;
    if (idx < 512 * 512) {
        int n = idx >> 9, k = idx & 511;
        W1t[idx] = f2bf(W1[k * 512 + n]);
    } else {
        int j = idx - 512 * 512;
        int n = j >> 9, k = j & 511;
        W2t[j] = (n < PT) ? f2bf(W2[k * PT + n]) : (unsigned short)0;
    }
}

// ---------------- conv weight prep (A-fragment order, bf16) ---------------
__global__ __launch_bounds__(256) void prep_cw_kernel(const float* __restrict__ rw1,
                                                      const float* __restrict__ rw2,
                                                      const float* __restrict__ rw3,
                                                      unsigned short* __restrict__ Wt1,
                                                      unsigned short* __restrict__ Wt2,
                                                      unsigned short* __restrict__ Wt3) {
    int idx = blockIdx.x * 256 + threadIdx.x;   // 15872 exact (62 blocks)
    if (idx < 4096) {
        int kb = idx >> 10, rem = idx & 1023, oc = rem >> 5, k = rem & 31;
        int tl = k >> 3, ic = k & 7, tap = kb * 4 + tl;
        Wt1[idx] = (tap < 15) ? f2bf(rw1[(oc * 8 + ic) * 15 + tap]) : (unsigned short)0;
    } else if (idx < 4096 + 7680) {
        int j = idx - 4096;
        int t = j >> 9, rem = j & 511, oc = rem >> 5, ic = rem & 31;
        Wt2[j] = f2bf(rw2[(oc * 32 + ic) * 15 + t]);
    } else {
        int j = idx - 11776;   // < 4096
        int kb = j >> 9, rem = j & 511, m = rem >> 5, k = rem & 31;
        int tl = k >> 4, ic = k & 15, tap = kb * 2 + tl;
        Wt3[j] = (m < 8 && tap < 15) ? f2bf(rw3[(m * 16 + ic) * 15 + tap]) : (unsigned short)0;
    }
}

// ---------------- bf16 MFMA GEMM, global_load_lds staging -----------------
// A: M x 512 bf16 row-major. Bt: N x 512 bf16. 128x128 tile, BK=32.
template<bool FUSE_GELU, bool OUT_BF16, int LOG2_NT>
__global__ __launch_bounds__(256) void gemm_lds_kernel(const unsigned short* __restrict__ A,
                                                       const unsigned short* __restrict__ Bt,
                                                       const float* __restrict__ bias,
                                                       void* __restrict__ Cout,
                                                       int out_stride, int n_valid) {
    __shared__ __align__(16) unsigned short As[128 * 32];
    __shared__ __align__(16) unsigned short Bs[128 * 32];
    const int tid  = threadIdx.x;
    const int lane = tid & 63;
    const int wid  = tid >> 6;
    const int bid  = blockIdx.x;
    const int nt   = (bid >> 3) & ((1 << LOG2_NT) - 1);
    const int mt   = (bid >> (3 + LOG2_NT)) * 8 + (bid & 7);
    const int m0 = mt * 128;
    const int n0 = nt * 128;
    const int mw = (wid >> 1) * 64;
    const int nw = (wid & 1) * 64;
    const int l15  = lane & 15;
    const int quad = lane >> 4;
    const int srow = lane >> 2;        // 0..15 within a 16-row chunk
    const int scol = (lane & 3) * 8;   // k-offset in shorts

    floatx4 acc[4][4];
#pragma unroll
    for (int i = 0; i < 4; ++i)
#pragma unroll
        for (int j = 0; j < 4; ++j) acc[i][j] = (floatx4)0.0f;

    for (int k0 = 0; k0 < 512; k0 += 32) {
#pragma unroll
        for (int p = 0; p < 2; ++p) {
            const int rbase = wid * 32 + p * 16;
            async16(A  + (size_t)(m0 + rbase + srow) * 512 + k0 + scol, As + rbase * 32);
            async16(Bt + (size_t)(n0 + rbase + srow) * 512 + k0 + scol, Bs + rbase * 32);
        }
        __syncthreads();
        bf16x8 af[4], bfr[4];
#pragma unroll
        for (int t = 0; t < 4; ++t) {
            af[t]  = *(const bf16x8*)(As + (mw + t * 16 + l15) * 32 + quad * 8);
            bfr[t] = *(const bf16x8*)(Bs + (nw + t * 16 + l15) * 32 + quad * 8);
        }
#pragma unroll
        for (int mtl = 0; mtl < 4; ++mtl)
#pragma unroll
            for (int ntl = 0; ntl < 4; ++ntl)
                acc[mtl][ntl] = __builtin_amdgcn_mfma_f32_16x16x32_bf16(af[mtl], bfr[ntl], acc[mtl][ntl], 0, 0, 0);
        __syncthreads();
    }

#pragma unroll
    for (int mtl = 0; mtl < 4; ++mtl) {
#pragma unroll
        for (int ntl = 0; ntl < 4; ++ntl) {
            const int col  = n0 + nw + ntl * 16 + l15;
            const int rowb = m0 + mw + mtl * 16 + quad * 4;
            const bool colok = (col < n_valid);
            float bv = colok ? bias[col] : 0.0f;
#pragma unroll
            for (int r = 0; r < 4; ++r) {
                float v = acc[mtl][ntl][r] + bv;
                if (FUSE_GELU) v = gelu_erf(v);
                if (colok) {
                    size_t off = (size_t)(rowb + r) * out_stride + col;
                    if (OUT_BF16) ((unsigned short*)Cout)[off] = f2bf(v);
                    else          ((float*)Cout)[off] = v;
                }
            }
        }
    }
}

// ---------------- fused tail: oadd + conv1 + conv2 + conv3 + res + pw -----
// One block = 192 output positions of one batch row (11 segs x 1024).
// LDS plan (37.6 KB -> 4 blocks/CU):
//   ys1  : 224 rows x 40 shorts (c1 tile, row0 = seg0-14)       17,920 B
//   ybuf : union { xs 240x8 shorts (rec bf16, row0 = seg0-21);
//                  ys2 208x24 shorts (c2 tile, row0 = seg0-7) }  9,984 B
//   r2   : 192 x 12 fp32 (rec central)                           9,216 B
//   consts                                                          512 B
// xs is dead after conv1 (barrier), ys2 written in conv2 -> safe overlay.
__global__ __launch_bounds__(256) void tail_fused(const unsigned short* __restrict__ pat,
                                                  const unsigned short* __restrict__ Wt1,
                                                  const float* __restrict__ rb1,
                                                  const unsigned short* __restrict__ Wt2,
                                                  const float* __restrict__ rb2,
                                                  const unsigned short* __restrict__ Wt3,
                                                  const float* __restrict__ rb3,
                                                  const float* __restrict__ pw,
                                                  const float* __restrict__ pb,
                                                  float* __restrict__ out) {
    __shared__ __align__(16) unsigned short ys1[224 * 40];
    __shared__ __align__(16) unsigned short ybuf[208 * 24];
    __shared__ __align__(16) float r2[192 * 12];
    __shared__ float pws[64], bs1[32], bs2[16], bs3[8], bsp[8];
    unsigned short* xs  = ybuf;   // 240 rows x 8 shorts
    unsigned short* ys2 = ybuf;   // 208 rows x 24 shorts
    const int tid = threadIdx.x;
    const int b = blockIdx.y;
    const int seg0 = blockIdx.x * 192;
    const int lane = tid & 63, wid = tid >> 6;
    const int l15 = lane & 15, quad = lane >> 4;

    if (tid < 64) pws[tid] = pw[tid];
    else if (tid < 96)  bs1[tid - 64]  = rb1[tid - 64];
    else if (tid < 112) bs2[tid - 96]  = rb2[tid - 96];
    else if (tid < 120) bs3[tid - 112] = rb3[tid - 112];
    else if (tid < 128) bsp[tid - 120] = pb[tid - 120];

    // ---- stage A: overlap-add -> xs (bf16, 240 rows) + r2 (fp32, 192) ----
    if (tid < 240) {
        const int row = tid;
        int p = seg0 - 21 + row;
        float acc[8];
#pragma unroll
        for (int c = 0; c < 8; ++c) acc[c] = 0.0f;
        if (p >= 0 && p < OL) {
            int imin = (p >= PT) ? (p - (PT - PSTRIDE)) / PSTRIDE : 0;
            int imax = p / PSTRIDE; if (imax > NP - 1) imax = NP - 1;
            float wsum = 0.0f;
            for (int i = imin; i <= imax; ++i) {
                int t = p - i * PSTRIDE;
                float w = (t < 50) ? t * (1.0f / 49.0f)
                                   : ((t >= 150) ? (199 - t) * (1.0f / 49.0f) : 1.0f);
                wsum += w;
                const unsigned short* pp = pat + ((size_t)(b * NP + i) * NC) * PT + t;
#pragma unroll
                for (int c = 0; c < 8; ++c) acc[c] += bf2f(pp[c * PT]) * w;
            }
            float inv = 1.0f / fmaxf(wsum, 1e-8f);
#pragma unroll
            for (int c = 0; c < 8; ++c) acc[c] *= inv;
        }
        ushort4 o0, o1;
        o0.x = f2bf(acc[0]); o0.y = f2bf(acc[1]); o0.z = f2bf(acc[2]); o0.w = f2bf(acc[3]);
        o1.x = f2bf(acc[4]); o1.y = f2bf(acc[5]); o1.z = f2bf(acc[6]); o1.w = f2bf(acc[7]);
        *(ushort4*)(xs + row * 8)     = o0;
        *(ushort4*)(xs + row * 8 + 4) = o1;
        int cr = row - 21;
        if (cr >= 0 && cr < 192) {
            float4 v0 = { acc[0], acc[1], acc[2], acc[3] };
            float4 v1 = { acc[4], acc[5], acc[6], acc[7] };
            *(float4*)(r2 + cr * 12)     = v0;
            *(float4*)(r2 + cr * 12 + 4) = v1;
        }
    }
    __syncthreads();

    // ---- conv1: 8 -> 32, k15, gelu -> ys1 (224 positions, 14 tiles) ----
    {
        bf16x8 wf[4][2];
#pragma unroll
        for (int kb = 0; kb < 4; ++kb)
#pragma unroll
            for (int ot = 0; ot < 2; ++ot)
                wf[kb][ot] = *(const bf16x8*)(Wt1 + (kb * 32 + ot * 16 + l15) * 32 + quad * 8);
#pragma unroll
        for (int u = 0; u < 4; ++u) {
            const int base = (u * 4 + wid) * 16;
            if (base < 224) {
                const int posl = base + l15;
                floatx4 a0 = (floatx4)0.0f, a1 = (floatx4)0.0f;
#pragma unroll
                for (int kb = 0; kb < 4; ++kb) {
                    int row = posl + kb * 4 + quad;
                    bf16x8 bfrag = *(const bf16x8*)(xs + row * 8);
                    a0 = __builtin_amdgcn_mfma_f32_16x16x32_bf16(wf[kb][0], bfrag, a0, 0, 0, 0);
                    a1 = __builtin_amdgcn_mfma_f32_16x16x32_bf16(wf[kb][1], bfrag, a1, 0, 0, 0);
                }
                int oc0 = quad * 4;
                ushort4 o;
                o.x = f2bf(gelu_erf(a0[0] + bs1[oc0]));
                o.y = f2bf(gelu_erf(a0[1] + bs1[oc0 + 1]));
                o.z = f2bf(gelu_erf(a0[2] + bs1[oc0 + 2]));
                o.w = f2bf(gelu_erf(a0[3] + bs1[oc0 + 3]));
                *(ushort4*)(ys1 + posl * 40 + oc0) = o;
                int oc1 = 16 + quad * 4;
                o.x = f2bf(gelu_erf(a1[0] + bs1[oc1]));
                o.y = f2bf(gelu_erf(a1[1] + bs1[oc1 + 1]));
                o.z = f2bf(gelu_erf(a1[2] + bs1[oc1 + 2]));
                o.w = f2bf(gelu_erf(a1[3] + bs1[oc1 + 3]));
                *(ushort4*)(ys1 + posl * 40 + oc1) = o;
            }
        }
    }
    __syncthreads();

    // ---- conv2: 32 -> 16, k15, gelu -> ys2 (208 positions, 13 tiles) ----
    // NOTE: ys2 overlays xs; xs was last read in conv1 (barrier above).
    {
        bf16x8 wf[15];
#pragma unroll
        for (int t = 0; t < 15; ++t)
            wf[t] = *(const bf16x8*)(Wt2 + (t * 16 + l15) * 32 + quad * 8);
#pragma unroll
        for (int u = 0; u < 4; ++u) {
            const int base = (u * 4 + wid) * 16;
            if (base < 208) {
                const int posl = base + l15;
                floatx4 a = (floatx4)0.0f;
#pragma unroll
                for (int t = 0; t < 15; ++t) {
                    bf16x8 bfrag = *(const bf16x8*)(ys1 + (posl + t) * 40 + quad * 8);
                    a = __builtin_amdgcn_mfma_f32_16x16x32_bf16(wf[t], bfrag, a, 0, 0, 0);
                }
                int oc0 = quad * 4;
                ushort4 o;
                o.x = f2bf(gelu_erf(a[0] + bs2[oc0]));
                o.y = f2bf(gelu_erf(a[1] + bs2[oc0 + 1]));
                o.z = f2bf(gelu_erf(a[2] + bs2[oc0 + 2]));
                o.w = f2bf(gelu_erf(a[3] + bs2[oc0 + 3]));
                *(ushort4*)(ys2 + posl * 24 + oc0) = o;
            }
        }
    }
    __syncthreads();

    // ---- conv3: 16 -> 8, k15, + residual (into r2) (192 pos, 12 tiles) ----
    {
        bf16x8 wf[8];
#pragma unroll
        for (int kb = 0; kb < 8; ++kb)
            wf[kb] = *(const bf16x8*)(Wt3 + (kb * 16 + l15) * 32 + quad * 8);
#pragma unroll
        for (int u = 0; u < 4; ++u) {
            const int base = (u * 4 + wid) * 16;
            if (base < 192) {
                const int posl = base + l15;
                floatx4 a = (floatx4)0.0f;
#pragma unroll
                for (int kb = 0; kb < 8; ++kb) {
                    int row = posl + kb * 2 + (quad >> 1);
                    bf16x8 bfrag = *(const bf16x8*)(ys2 + row * 24 + (quad & 1) * 8);
                    a = __builtin_amdgcn_mfma_f32_16x16x32_bf16(wf[kb], bfrag, a, 0, 0, 0);
                }
                if (quad < 2) {
                    int oc0 = quad * 4;
                    float4 rv = *(const float4*)(r2 + posl * 12 + oc0);
                    rv.x += a[0] + bs3[oc0];
                    rv.y += a[1] + bs3[oc0 + 1];
                    rv.z += a[2] + bs3[oc0 + 2];
                    rv.w += a[3] + bs3[oc0 + 3];
                    *(float4*)(r2 + posl * 12 + oc0) = rv;
                }
            }
        }
    }
    __syncthreads();

    // ---- pointwise 8x8 + store ----
    if (tid < 192) {
        int p = seg0 + tid;
        if (p < OL) {
            float4 a = *(const float4*)(r2 + tid * 12);
            float4 c = *(const float4*)(r2 + tid * 12 + 4);
#pragma unroll
            for (int o = 0; o < 8; ++o) {
                float v = bsp[o];
                v += pws[o * 8 + 0] * a.x + pws[o * 8 + 1] * a.y + pws[o * 8 + 2] * a.z + pws[o * 8 + 3] * a.w;
                v += pws[o * 8 + 4] * c.x + pws[o * 8 + 5] * c.y + pws[o * 8 + 6] * c.z + pws[o * 8 + 7] * c.w;
                out[((size_t)b * 8 + o) * OL + p] = v;
            }
        }
    }
}

// ---------------------------------------------------------------------------
extern "C" void kernel_launch(void* const* d_in, const int* in_sizes, int n_in,
                              void* d_out, int out_size, void* d_ws, size_t ws_size,
                              hipStream_t stream) {
    const float* X   = (const float*)d_in[0];
    const float* W1  = (const float*)d_in[1];
    const float* b1  = (const float*)d_in[2];
    const float* W2  = (const float*)d_in[3];
    const float* b2  = (const float*)d_in[4];
    const float* rw1 = (const float*)d_in[5];
    const float* rb1 = (const float*)d_in[6];
    const float* rw2 = (const float*)d_in[7];
    const float* rb2 = (const float*)d_in[8];
    const float* rw3 = (const float*)d_in[9];
    const float* rb3 = (const float*)d_in[10];
    const float* pw  = (const float*)d_in[11];
    const float* pb  = (const float*)d_in[12];
    float* out = (float*)d_out;

    char* ws = (char*)d_ws;
    unsigned short* Xb  = (unsigned short*)(ws);               //  92,274,688
    unsigned short* W1t = (unsigned short*)(ws +  92274688);   //     524,288
    unsigned short* W2t = (unsigned short*)(ws +  92798976);   //     262,144
    unsigned short* h   = (unsigned short*)(ws +  93061120);   //  92,274,688
    unsigned short* pat = (unsigned short*)(ws + 185335808);   //  36,044,800 (bf16 patches)
    unsigned short* Wt1 = (unsigned short*)(ws + 322961408);   //       8,192
    unsigned short* Wt2 = (unsigned short*)(ws + 322969600);   //      15,360
    unsigned short* Wt3 = (unsigned short*)(ws + 322984960);   //       8,192

    cast_x_kernel<<<45056, 256, 0, stream>>>(X, Xb);
    prep_w_kernel<<<1536, 256, 0, stream>>>(W1, W2, W1t, W2t);
    prep_cw_kernel<<<62, 256, 0, stream>>>(rw1, rw2, rw3, Wt1, Wt2, Wt3);
    gemm_lds_kernel<true,  true, 2><<<2816, 256, 0, stream>>>(Xb, W1t, b1, (void*)h,   512, 512);
    gemm_lds_kernel<false, true, 1><<<1408, 256, 0, stream>>>(h,  W2t, b2, (void*)pat, 200, 200);
    tail_fused<<<dim3(11, NB), 256, 0, stream>>>(pat, Wt1, rb1, Wt2, rb2, Wt3, rb3, pw, pb, out);
}

// Round 4
// 554.799 us; speedup vs baseline: 1.0953x; 1.0192x over previous
//
#include <hip/hip_runtime.h>
#include <stdint.h>
#include <stddef.h>

#define HD 512
#define NP 11
#define PT 200
#define PSTRIDE 180
#define OL 2000
#define NC 8
#define NB 1024

typedef __bf16 bf16x8 __attribute__((ext_vector_type(8)));
typedef float floatx4 __attribute__((ext_vector_type(4)));

// native RNE f32->bf16 (pairs into v_cvt_pk_bf16_f32); bit-identical to the
// +0x7FFF rounding trick for finite values.
__device__ __forceinline__ unsigned short f2bf(float f) {
    return __builtin_bit_cast(unsigned short, (__bf16)f);
}
__device__ __forceinline__ float bf2f(unsigned short s) {
    return __uint_as_float(((unsigned int)s) << 16);
}
// branch-free GELU(erf): A&S 7.1.26, |erf err| < 1.5e-7 absolute.
// No divergent range split (libm erff branches at |x|~1); ~15 VALU ops.
__device__ __forceinline__ float gelu_erf(float x) {
    float z  = x * 0.70710678118654752440f;
    float az = __builtin_fabsf(z);
    float t  = __builtin_amdgcn_rcpf(__builtin_fmaf(0.3275911f, az, 1.0f));
    float p  = __builtin_fmaf(1.061405429f, t, -1.453152027f);
    p = __builtin_fmaf(p, t, 1.421413741f);
    p = __builtin_fmaf(p, t, -0.284496736f);
    p = __builtin_fmaf(p, t, 0.254829592f);
    p = p * t;
    float e    = __expf(-az * az);
    float erfa = __builtin_fmaf(-p, e, 1.0f);   // erf(|z|)
    float erfz = (z < 0.0f) ? -erfa : erfa;
    return 0.5f * x * (1.0f + erfz);
}
// async global->LDS, 16B per lane; lptr must be wave-uniform (HW: base + lane*16)
__device__ __forceinline__ void async16(const unsigned short* g, unsigned short* l) {
    __builtin_amdgcn_global_load_lds(
        (const __attribute__((address_space(1))) unsigned int*)g,
        (__attribute__((address_space(3))) unsigned int*)l, 16, 0, 0);
}

// ---------------- cast X fp32 -> bf16 ------------------------------------
__global__ __launch_bounds__(256) void cast_x_kernel(const float* __restrict__ x,
                                                     unsigned short* __restrict__ xb) {
    int idx = blockIdx.x * 256 + threadIdx.x;
    float4 v = ((const float4*)x)[idx];
    ushort4 o;
    o.x = f2bf(v.x); o.y = f2bf(v.y); o.z = f2bf(v.z); o.w = f2bf(v.w);
    ((ushort4*)xb)[idx] = o;
}

// ---------------- GEMM weight prep ---------------------------------------
__global__ __launch_bounds__(256) void prep_w_kernel(const float* __restrict__ W1,
                                                     const float* __restrict__ W2,
                                                     unsigned short* __restrict__ W1t,
                                                     unsigned short* __restrict__ W2t) {
    int idx = blockIdx.x * 256 + threadIdx.x;
    if (idx < 512 * 512) {
        int n = idx >> 9, k = idx & 511;
        W1t[idx] = f2bf(W1[k * 512 + n]);
    } else {
        int j = idx - 512 * 512;
        int n = j >> 9, k = j & 511;
        W2t[j] = (n < PT) ? f2bf(W2[k * PT + n]) : (unsigned short)0;
    }
}

// ---------------- conv weight prep (A-fragment order, bf16) ---------------
__global__ __launch_bounds__(256) void prep_cw_kernel(const float* __restrict__ rw1,
                                                      const float* __restrict__ rw2,
                                                      const float* __restrict__ rw3,
                                                      unsigned short* __restrict__ Wt1,
                                                      unsigned short* __restrict__ Wt2,
                                                      unsigned short* __restrict__ Wt3) {
    int idx = blockIdx.x * 256 + threadIdx.x;   // 15872 exact (62 blocks)
    if (idx < 4096) {
        int kb = idx >> 10, rem = idx & 1023, oc = rem >> 5, k = rem & 31;
        int tl = k >> 3, ic = k & 7, tap = kb * 4 + tl;
        Wt1[idx] = (tap < 15) ? f2bf(rw1[(oc * 8 + ic) * 15 + tap]) : (unsigned short)0;
    } else if (idx < 4096 + 7680) {
        int j = idx - 4096;
        int t = j >> 9, rem = j & 511, oc = rem >> 5, ic = rem & 31;
        Wt2[j] = f2bf(rw2[(oc * 32 + ic) * 15 + t]);
    } else {
        int j = idx - 11776;   // < 4096
        int kb = j >> 9, rem = j & 511, m = rem >> 5, k = rem & 31;
        int tl = k >> 4, ic = k & 15, tap = kb * 2 + tl;
        Wt3[j] = (m < 8 && tap < 15) ? f2bf(rw3[(m * 16 + ic) * 15 + tap]) : (unsigned short)0;
    }
}

// ---------------- bf16 MFMA GEMM, global_load_lds staging -----------------
// A: M x 512 bf16 row-major. Bt: N x 512 bf16. 128x128 tile, BK=32.
template<bool FUSE_GELU, bool OUT_BF16, int LOG2_NT>
__global__ __launch_bounds__(256) void gemm_lds_kernel(const unsigned short* __restrict__ A,
                                                       const unsigned short* __restrict__ Bt,
                                                       const float* __restrict__ bias,
                                                       void* __restrict__ Cout,
                                                       int out_stride, int n_valid) {
    __shared__ __align__(16) unsigned short As[128 * 32];
    __shared__ __align__(16) unsigned short Bs[128 * 32];
    const int tid  = threadIdx.x;
    const int lane = tid & 63;
    const int wid  = tid >> 6;
    const int bid  = blockIdx.x;
    const int nt   = (bid >> 3) & ((1 << LOG2_NT) - 1);
    const int mt   = (bid >> (3 + LOG2_NT)) * 8 + (bid & 7);
    const int m0 = mt * 128;
    const int n0 = nt * 128;
    const int mw = (wid >> 1) * 64;
    const int nw = (wid & 1) * 64;
    const int l15  = lane & 15;
    const int quad = lane >> 4;
    const int srow = lane >> 2;        // 0..15 within a 16-row chunk
    const int scol = (lane & 3) * 8;   // k-offset in shorts

    floatx4 acc[4][4];
#pragma unroll
    for (int i = 0; i < 4; ++i)
#pragma unroll
        for (int j = 0; j < 4; ++j) acc[i][j] = (floatx4)0.0f;

    for (int k0 = 0; k0 < 512; k0 += 32) {
#pragma unroll
        for (int p = 0; p < 2; ++p) {
            const int rbase = wid * 32 + p * 16;
            async16(A  + (size_t)(m0 + rbase + srow) * 512 + k0 + scol, As + rbase * 32);
            async16(Bt + (size_t)(n0 + rbase + srow) * 512 + k0 + scol, Bs + rbase * 32);
        }
        __syncthreads();
        bf16x8 af[4], bfr[4];
#pragma unroll
        for (int t = 0; t < 4; ++t) {
            af[t]  = *(const bf16x8*)(As + (mw + t * 16 + l15) * 32 + quad * 8);
            bfr[t] = *(const bf16x8*)(Bs + (nw + t * 16 + l15) * 32 + quad * 8);
        }
#pragma unroll
        for (int mtl = 0; mtl < 4; ++mtl)
#pragma unroll
            for (int ntl = 0; ntl < 4; ++ntl)
                acc[mtl][ntl] = __builtin_amdgcn_mfma_f32_16x16x32_bf16(af[mtl], bfr[ntl], acc[mtl][ntl], 0, 0, 0);
        __syncthreads();
    }

#pragma unroll
    for (int mtl = 0; mtl < 4; ++mtl) {
#pragma unroll
        for (int ntl = 0; ntl < 4; ++ntl) {
            const int col  = n0 + nw + ntl * 16 + l15;
            const int rowb = m0 + mw + mtl * 16 + quad * 4;
            const bool colok = (col < n_valid);
            float bv = colok ? bias[col] : 0.0f;
#pragma unroll
            for (int r = 0; r < 4; ++r) {
                float v = acc[mtl][ntl][r] + bv;
                if (FUSE_GELU) v = gelu_erf(v);
                if (colok) {
                    size_t off = (size_t)(rowb + r) * out_stride + col;
                    if (OUT_BF16) ((unsigned short*)Cout)[off] = f2bf(v);
                    else          ((float*)Cout)[off] = v;
                }
            }
        }
    }
}

// ---------------- fused tail: oadd + conv1 + conv2 + conv3 + res + pw -----
// One block = 256 output positions of one batch row. The full rec/c1/c2
// chain lives in LDS with a 21-position halo; only pat is read and only
// out is written to HBM. (256-tile geometry: measured faster than 192-tile
// at 4 blocks/CU -- halo overcompute dominates the occupancy gain.)
__global__ __launch_bounds__(256) void tail_fused(const unsigned short* __restrict__ pat,
                                                  const unsigned short* __restrict__ Wt1,
                                                  const float* __restrict__ rb1,
                                                  const unsigned short* __restrict__ Wt2,
                                                  const float* __restrict__ rb2,
                                                  const unsigned short* __restrict__ Wt3,
                                                  const float* __restrict__ rb3,
                                                  const float* __restrict__ pw,
                                                  const float* __restrict__ pb,
                                                  float* __restrict__ out) {
    __shared__ __align__(16) unsigned short xs[304 * 8];    // rec bf16, row0 = seg0-21
    __shared__ __align__(16) unsigned short ys1[288 * 40];  // c1 tile,  row0 = seg0-14
    __shared__ __align__(16) unsigned short ys2[272 * 24];  // c2 tile,  row0 = seg0-7
    __shared__ __align__(16) float r2[256 * 12];            // rec fp32, central 256
    __shared__ float pws[64], bs1[32], bs2[16], bs3[8], bsp[8];
    const int tid = threadIdx.x;
    const int b = blockIdx.y;
    const int seg0 = blockIdx.x * 256;
    const int lane = tid & 63, wid = tid >> 6;
    const int l15 = lane & 15, quad = lane >> 4;

    if (tid < 64) pws[tid] = pw[tid];
    else if (tid < 96)  bs1[tid - 64]  = rb1[tid - 64];
    else if (tid < 112) bs2[tid - 96]  = rb2[tid - 96];
    else if (tid < 120) bs3[tid - 112] = rb3[tid - 112];
    else if (tid < 128) bsp[tid - 120] = pb[tid - 120];

    // ---- stage A: overlap-add -> xs (bf16, 304 rows) + r2 (fp32, 256) ----
    for (int row = tid; row < 304; row += 256) {
        int p = seg0 - 21 + row;
        float acc[8];
#pragma unroll
        for (int c = 0; c < 8; ++c) acc[c] = 0.0f;
        if (p >= 0 && p < OL) {
            int imin = (p >= PT) ? (p - (PT - PSTRIDE)) / PSTRIDE : 0;
            int imax = p / PSTRIDE; if (imax > NP - 1) imax = NP - 1;
            float wsum = 0.0f;
            for (int i = imin; i <= imax; ++i) {
                int t = p - i * PSTRIDE;
                float w = (t < 50) ? t * (1.0f / 49.0f)
                                   : ((t >= 150) ? (199 - t) * (1.0f / 49.0f) : 1.0f);
                wsum += w;
                const unsigned short* pp = pat + ((size_t)(b * NP + i) * NC) * PT + t;
#pragma unroll
                for (int c = 0; c < 8; ++c) acc[c] += bf2f(pp[c * PT]) * w;
            }
            float inv = 1.0f / fmaxf(wsum, 1e-8f);
#pragma unroll
            for (int c = 0; c < 8; ++c) acc[c] *= inv;
        }
        ushort4 o0, o1;
        o0.x = f2bf(acc[0]); o0.y = f2bf(acc[1]); o0.z = f2bf(acc[2]); o0.w = f2bf(acc[3]);
        o1.x = f2bf(acc[4]); o1.y = f2bf(acc[5]); o1.z = f2bf(acc[6]); o1.w = f2bf(acc[7]);
        *(ushort4*)(xs + row * 8)     = o0;
        *(ushort4*)(xs + row * 8 + 4) = o1;
        int cr = row - 21;
        if (cr >= 0 && cr < 256) {
            float4 v0 = { acc[0], acc[1], acc[2], acc[3] };
            float4 v1 = { acc[4], acc[5], acc[6], acc[7] };
            *(float4*)(r2 + cr * 12)     = v0;
            *(float4*)(r2 + cr * 12 + 4) = v1;
        }
    }
    __syncthreads();

    // ---- conv1: 8 -> 32, k15, gelu -> ys1 (288 positions) ----
    {
        bf16x8 wf[4][2];
#pragma unroll
        for (int kb = 0; kb < 4; ++kb)
#pragma unroll
            for (int ot = 0; ot < 2; ++ot)
                wf[kb][ot] = *(const bf16x8*)(Wt1 + (kb * 32 + ot * 16 + l15) * 32 + quad * 8);
#pragma unroll
        for (int u = 0; u < 5; ++u) {
            const int base = wid * 80 + u * 16;
            if (base < 288) {
                const int posl = base + l15;
                floatx4 a0 = (floatx4)0.0f, a1 = (floatx4)0.0f;
#pragma unroll
                for (int kb = 0; kb < 4; ++kb) {
                    int row = posl + kb * 4 + quad;
                    bf16x8 bfrag = *(const bf16x8*)(xs + row * 8);
                    a0 = __builtin_amdgcn_mfma_f32_16x16x32_bf16(wf[kb][0], bfrag, a0, 0, 0, 0);
                    a1 = __builtin_amdgcn_mfma_f32_16x16x32_bf16(wf[kb][1], bfrag, a1, 0, 0, 0);
                }
                int oc0 = quad * 4;
                ushort4 o;
                o.x = f2bf(gelu_erf(a0[0] + bs1[oc0]));
                o.y = f2bf(gelu_erf(a0[1] + bs1[oc0 + 1]));
                o.z = f2bf(gelu_erf(a0[2] + bs1[oc0 + 2]));
                o.w = f2bf(gelu_erf(a0[3] + bs1[oc0 + 3]));
                *(ushort4*)(ys1 + posl * 40 + oc0) = o;
                int oc1 = 16 + quad * 4;
                o.x = f2bf(gelu_erf(a1[0] + bs1[oc1]));
                o.y = f2bf(gelu_erf(a1[1] + bs1[oc1 + 1]));
                o.z = f2bf(gelu_erf(a1[2] + bs1[oc1 + 2]));
                o.w = f2bf(gelu_erf(a1[3] + bs1[oc1 + 3]));
                *(ushort4*)(ys1 + posl * 40 + oc1) = o;
            }
        }
    }
    __syncthreads();

    // ---- conv2: 32 -> 16, k15, gelu -> ys2 (272 positions) ----
    {
        bf16x8 wf[15];
#pragma unroll
        for (int t = 0; t < 15; ++t)
            wf[t] = *(const bf16x8*)(Wt2 + (t * 16 + l15) * 32 + quad * 8);
#pragma unroll
        for (int u = 0; u < 5; ++u) {
            const int base = wid * 80 + u * 16;
            if (base < 272) {
                const int posl = base + l15;
                floatx4 a = (floatx4)0.0f;
#pragma unroll
                for (int t = 0; t < 15; ++t) {
                    bf16x8 bfrag = *(const bf16x8*)(ys1 + (posl + t) * 40 + quad * 8);
                    a = __builtin_amdgcn_mfma_f32_16x16x32_bf16(wf[t], bfrag, a, 0, 0, 0);
                }
                int oc0 = quad * 4;
                ushort4 o;
                o.x = f2bf(gelu_erf(a[0] + bs2[oc0]));
                o.y = f2bf(gelu_erf(a[1] + bs2[oc0 + 1]));
                o.z = f2bf(gelu_erf(a[2] + bs2[oc0 + 2]));
                o.w = f2bf(gelu_erf(a[3] + bs2[oc0 + 3]));
                *(ushort4*)(ys2 + posl * 24 + oc0) = o;
            }
        }
    }
    __syncthreads();

    // ---- conv3: 16 -> 8, k15, + residual (into r2) ----
    {
        bf16x8 wf[8];
#pragma unroll
        for (int kb = 0; kb < 8; ++kb)
            wf[kb] = *(const bf16x8*)(Wt3 + (kb * 16 + l15) * 32 + quad * 8);
#pragma unroll
        for (int u = 0; u < 5; ++u) {
            const int base = wid * 80 + u * 16;
            if (base < 256) {
                const int posl = base + l15;
                floatx4 a = (floatx4)0.0f;
#pragma unroll
                for (int kb = 0; kb < 8; ++kb) {
                    int row = posl + kb * 2 + (quad >> 1);
                    bf16x8 bfrag = *(const bf16x8*)(ys2 + row * 24 + (quad & 1) * 8);
                    a = __builtin_amdgcn_mfma_f32_16x16x32_bf16(wf[kb], bfrag, a, 0, 0, 0);
                }
                if (quad < 2) {
                    int oc0 = quad * 4;
                    float4 rv = *(const float4*)(r2 + posl * 12 + oc0);
                    rv.x += a[0] + bs3[oc0];
                    rv.y += a[1] + bs3[oc0 + 1];
                    rv.z += a[2] + bs3[oc0 + 2];
                    rv.w += a[3] + bs3[oc0 + 3];
                    *(float4*)(r2 + posl * 12 + oc0) = rv;
                }
            }
        }
    }
    __syncthreads();

    // ---- pointwise 8x8 + store ----
    {
        int p = seg0 + tid;
        if (p < OL) {
            float4 a = *(const float4*)(r2 + tid * 12);
            float4 c = *(const float4*)(r2 + tid * 12 + 4);
#pragma unroll
            for (int o = 0; o < 8; ++o) {
                float v = bsp[o];
                v += pws[o * 8 + 0] * a.x + pws[o * 8 + 1] * a.y + pws[o * 8 + 2] * a.z + pws[o * 8 + 3] * a.w;
                v += pws[o * 8 + 4] * c.x + pws[o * 8 + 5] * c.y + pws[o * 8 + 6] * c.z + pws[o * 8 + 7] * c.w;
                out[((size_t)b * 8 + o) * OL + p] = v;
            }
        }
    }
}

// ---------------------------------------------------------------------------
extern "C" void kernel_launch(void* const* d_in, const int* in_sizes, int n_in,
                              void* d_out, int out_size, void* d_ws, size_t ws_size,
                              hipStream_t stream) {
    const float* X   = (const float*)d_in[0];
    const float* W1  = (const float*)d_in[1];
    const float* b1  = (const float*)d_in[2];
    const float* W2  = (const float*)d_in[3];
    const float* b2  = (const float*)d_in[4];
    const float* rw1 = (const float*)d_in[5];
    const float* rb1 = (const float*)d_in[6];
    const float* rw2 = (const float*)d_in[7];
    const float* rb2 = (const float*)d_in[8];
    const float* rw3 = (const float*)d_in[9];
    const float* rb3 = (const float*)d_in[10];
    const float* pw  = (const float*)d_in[11];
    const float* pb  = (const float*)d_in[12];
    float* out = (float*)d_out;

    char* ws = (char*)d_ws;
    unsigned short* Xb  = (unsigned short*)(ws);               //  92,274,688
    unsigned short* W1t = (unsigned short*)(ws +  92274688);   //     524,288
    unsigned short* W2t = (unsigned short*)(ws +  92798976);   //     262,144
    unsigned short* h   = (unsigned short*)(ws +  93061120);   //  92,274,688
    unsigned short* pat = (unsigned short*)(ws + 185335808);   //  36,044,800 (bf16 patches)
    unsigned short* Wt1 = (unsigned short*)(ws + 322961408);   //       8,192
    unsigned short* Wt2 = (unsigned short*)(ws + 322969600);   //      15,360
    unsigned short* Wt3 = (unsigned short*)(ws + 322984960);   //       8,192

    cast_x_kernel<<<45056, 256, 0, stream>>>(X, Xb);
    prep_w_kernel<<<1536, 256, 0, stream>>>(W1, W2, W1t, W2t);
    prep_cw_kernel<<<62, 256, 0, stream>>>(rw1, rw2, rw3, Wt1, Wt2, Wt3);
    gemm_lds_kernel<true,  true, 2><<<2816, 256, 0, stream>>>(Xb, W1t, b1, (void*)h,   512, 512);
    gemm_lds_kernel<false, true, 1><<<1408, 256, 0, stream>>>(h,  W2t, b2, (void*)pat, 200, 200);
    tail_fused<<<dim3(8, NB), 256, 0, stream>>>(pat, Wt1, rb1, Wt2, rb2, Wt3, rb3, pw, pb, out);
}

// Round 5
// 548.061 us; speedup vs baseline: 1.1088x; 1.0123x over previous
//
#include <hip/hip_runtime.h>
#include <stdint.h>
#include <stddef.h>

#define HD 512
#define NP 11
#define PT 200
#define PSTRIDE 180
#define OL 2000
#define NC 8
#define NB 1024

typedef __bf16 bf16x8 __attribute__((ext_vector_type(8)));
typedef float floatx4 __attribute__((ext_vector_type(4)));
typedef unsigned short ushort8v __attribute__((ext_vector_type(8)));

// native RNE f32->bf16 (pairs into v_cvt_pk_bf16_f32); bit-identical to the
// +0x7FFF rounding trick for finite values.
__device__ __forceinline__ unsigned short f2bf(float f) {
    return __builtin_bit_cast(unsigned short, (__bf16)f);
}
__device__ __forceinline__ float bf2f(unsigned short s) {
    return __uint_as_float(((unsigned int)s) << 16);
}
// branch-free GELU(erf): A&S 7.1.26, |erf err| < 1.5e-7 absolute.
__device__ __forceinline__ float gelu_erf(float x) {
    float z  = x * 0.70710678118654752440f;
    float az = __builtin_fabsf(z);
    float t  = __builtin_amdgcn_rcpf(__builtin_fmaf(0.3275911f, az, 1.0f));
    float p  = __builtin_fmaf(1.061405429f, t, -1.453152027f);
    p = __builtin_fmaf(p, t, 1.421413741f);
    p = __builtin_fmaf(p, t, -0.284496736f);
    p = __builtin_fmaf(p, t, 0.254829592f);
    p = p * t;
    float e    = __expf(-az * az);
    float erfa = __builtin_fmaf(-p, e, 1.0f);   // erf(|z|)
    float erfz = (z < 0.0f) ? -erfa : erfa;
    return 0.5f * x * (1.0f + erfz);
}
// async global->LDS, 16B per lane; lptr must be wave-uniform (HW: base + lane*16)
__device__ __forceinline__ void async16(const unsigned short* g, unsigned short* l) {
    __builtin_amdgcn_global_load_lds(
        (const __attribute__((address_space(1))) unsigned int*)g,
        (__attribute__((address_space(3))) unsigned int*)l, 16, 0, 0);
}

// ---------------- GEMM weight prep ---------------------------------------
__global__ __launch_bounds__(256) void prep_w_kernel(const float* __restrict__ W1,
                                                     const float* __restrict__ W2,
                                                     unsigned short* __restrict__ W1t,
                                                     unsigned short* __restrict__ W2t) {
    int idx = blockIdx.x * 256 + threadIdx.x;
    if (idx < 512 * 512) {
        int n = idx >> 9, k = idx & 511;
        W1t[idx] = f2bf(W1[k * 512 + n]);
    } else {
        int j = idx - 512 * 512;
        int n = j >> 9, k = j & 511;
        W2t[j] = (n < PT) ? f2bf(W2[k * PT + n]) : (unsigned short)0;
    }
}

// ---------------- conv weight prep (A-fragment order, bf16) ---------------
__global__ __launch_bounds__(256) void prep_cw_kernel(const float* __restrict__ rw1,
                                                      const float* __restrict__ rw2,
                                                      const float* __restrict__ rw3,
                                                      unsigned short* __restrict__ Wt1,
                                                      unsigned short* __restrict__ Wt2,
                                                      unsigned short* __restrict__ Wt3) {
    int idx = blockIdx.x * 256 + threadIdx.x;   // 15872 exact (62 blocks)
    if (idx < 4096) {
        int kb = idx >> 10, rem = idx & 1023, oc = rem >> 5, k = rem & 31;
        int tl = k >> 3, ic = k & 7, tap = kb * 4 + tl;
        Wt1[idx] = (tap < 15) ? f2bf(rw1[(oc * 8 + ic) * 15 + tap]) : (unsigned short)0;
    } else if (idx < 4096 + 7680) {
        int j = idx - 4096;
        int t = j >> 9, rem = j & 511, oc = rem >> 5, ic = rem & 31;
        Wt2[j] = f2bf(rw2[(oc * 32 + ic) * 15 + t]);
    } else {
        int j = idx - 11776;   // < 4096
        int kb = j >> 9, rem = j & 511, m = rem >> 5, k = rem & 31;
        int tl = k >> 4, ic = k & 15, tap = kb * 2 + tl;
        Wt3[j] = (m < 8 && tap < 15) ? f2bf(rw3[(m * 16 + ic) * 15 + tap]) : (unsigned short)0;
    }
}

// ---------------- bf16 MFMA GEMM, global_load_lds staging -----------------
// A: M x 512 row-major; bf16 (async16 path) or fp32 (reg-staged cvt path,
// fuses the X fp32->bf16 cast into the K-loop). Bt: N x 512 bf16.
// 128x128 tile, BK=32. 1-D swizzled grid: nt=(bid>>3)&(NT-1),
// mt=(bid>>(3+L))*8+(bid&7) so same-XCD blocks share one A-tile in L2.
template<bool A_FP32, bool FUSE_GELU, bool OUT_BF16, int LOG2_NT>
__global__ __launch_bounds__(256) void gemm_lds_kernel(const void* __restrict__ Ain,
                                                       const unsigned short* __restrict__ Bt,
                                                       const float* __restrict__ bias,
                                                       void* __restrict__ Cout,
                                                       int out_stride, int n_valid) {
    __shared__ __align__(16) unsigned short As[128 * 32];
    __shared__ __align__(16) unsigned short Bs[128 * 32];
    const float* Af          = (const float*)Ain;
    const unsigned short* Ab = (const unsigned short*)Ain;
    const int tid  = threadIdx.x;
    const int lane = tid & 63;
    const int wid  = tid >> 6;
    const int bid  = blockIdx.x;
    const int nt   = (bid >> 3) & ((1 << LOG2_NT) - 1);
    const int mt   = (bid >> (3 + LOG2_NT)) * 8 + (bid & 7);
    const int m0 = mt * 128;
    const int n0 = nt * 128;
    const int mw = (wid >> 1) * 64;
    const int nw = (wid & 1) * 64;
    const int l15  = lane & 15;
    const int quad = lane >> 4;
    const int srow = lane >> 2;        // 0..15 within a 16-row chunk
    const int scol = (lane & 3) * 8;   // k-offset in shorts

    floatx4 acc[4][4];
#pragma unroll
    for (int i = 0; i < 4; ++i)
#pragma unroll
        for (int j = 0; j < 4; ++j) acc[i][j] = (floatx4)0.0f;

    float4 pv[2][2];
    auto loadA = [&](int k0) {
#pragma unroll
        for (int p = 0; p < 2; ++p) {
            const float* g = Af + (size_t)(m0 + wid * 32 + p * 16 + srow) * 512 + k0 + scol;
            pv[p][0] = *(const float4*)g;
            pv[p][1] = *(const float4*)(g + 4);
        }
    };
    if (A_FP32) loadA(0);

    for (int k0 = 0; k0 < 512; k0 += 32) {
#pragma unroll
        for (int p = 0; p < 2; ++p) {
            const int rbase = wid * 32 + p * 16;
            if (A_FP32) {
                ushort8v o;
                o[0] = f2bf(pv[p][0].x); o[1] = f2bf(pv[p][0].y);
                o[2] = f2bf(pv[p][0].z); o[3] = f2bf(pv[p][0].w);
                o[4] = f2bf(pv[p][1].x); o[5] = f2bf(pv[p][1].y);
                o[6] = f2bf(pv[p][1].z); o[7] = f2bf(pv[p][1].w);
                *(ushort8v*)(As + (rbase + srow) * 32 + scol) = o;
            } else {
                async16(Ab + (size_t)(m0 + rbase + srow) * 512 + k0 + scol, As + rbase * 32);
            }
            async16(Bt + (size_t)(n0 + rbase + srow) * 512 + k0 + scol, Bs + rbase * 32);
        }
        __syncthreads();   // drains B async (+A ds_writes); next-iter A loads not yet issued
        if (A_FP32 && k0 + 32 < 512) loadA(k0 + 32);   // latency hides under frags+MFMA
        bf16x8 af[4], bfr[4];
#pragma unroll
        for (int t = 0; t < 4; ++t) {
            af[t]  = *(const bf16x8*)(As + (mw + t * 16 + l15) * 32 + quad * 8);
            bfr[t] = *(const bf16x8*)(Bs + (nw + t * 16 + l15) * 32 + quad * 8);
        }
#pragma unroll
        for (int mtl = 0; mtl < 4; ++mtl)
#pragma unroll
            for (int ntl = 0; ntl < 4; ++ntl)
                acc[mtl][ntl] = __builtin_amdgcn_mfma_f32_16x16x32_bf16(af[mtl], bfr[ntl], acc[mtl][ntl], 0, 0, 0);
        __syncthreads();
    }

#pragma unroll
    for (int mtl = 0; mtl < 4; ++mtl) {
#pragma unroll
        for (int ntl = 0; ntl < 4; ++ntl) {
            const int col  = n0 + nw + ntl * 16 + l15;
            const int rowb = m0 + mw + mtl * 16 + quad * 4;
            const bool colok = (col < n_valid);
            float bv = colok ? bias[col] : 0.0f;
#pragma unroll
            for (int r = 0; r < 4; ++r) {
                float v = acc[mtl][ntl][r] + bv;
                if (FUSE_GELU) v = gelu_erf(v);
                if (colok) {
                    size_t off = (size_t)(rowb + r) * out_stride + col;
                    if (OUT_BF16) ((unsigned short*)Cout)[off] = f2bf(v);
                    else          ((float*)Cout)[off] = v;
                }
            }
        }
    }
}

// ---------------- fused tail: oadd + conv1 + conv2 + conv3 + res + pw -----
// One block = 256 output positions of one batch row. The full rec/c1/c2
// chain lives in LDS with a 21-position halo; only pat is read and only
// out is written to HBM.
__global__ __launch_bounds__(256) void tail_fused(const unsigned short* __restrict__ pat,
                                                  const unsigned short* __restrict__ Wt1,
                                                  const float* __restrict__ rb1,
                                                  const unsigned short* __restrict__ Wt2,
                                                  const float* __restrict__ rb2,
                                                  const unsigned short* __restrict__ Wt3,
                                                  const float* __restrict__ rb3,
                                                  const float* __restrict__ pw,
                                                  const float* __restrict__ pb,
                                                  float* __restrict__ out) {
    __shared__ __align__(16) unsigned short xs[304 * 8];    // rec bf16, row0 = seg0-21
    __shared__ __align__(16) unsigned short ys1[288 * 40];  // c1 tile,  row0 = seg0-14
    __shared__ __align__(16) unsigned short ys2[272 * 24];  // c2 tile,  row0 = seg0-7
    __shared__ __align__(16) float r2[256 * 12];            // rec fp32, central 256
    __shared__ float pws[64], bs1[32], bs2[16], bs3[8], bsp[8];
    const int tid = threadIdx.x;
    const int b = blockIdx.y;
    const int seg0 = blockIdx.x * 256;
    const int lane = tid & 63, wid = tid >> 6;
    const int l15 = lane & 15, quad = lane >> 4;

    if (tid < 64) pws[tid] = pw[tid];
    else if (tid < 96)  bs1[tid - 64]  = rb1[tid - 64];
    else if (tid < 112) bs2[tid - 96]  = rb2[tid - 96];
    else if (tid < 120) bs3[tid - 112] = rb3[tid - 112];
    else if (tid < 128) bsp[tid - 120] = pb[tid - 120];

    // ---- stage A: overlap-add -> xs (bf16, 304 rows) + r2 (fp32, 256) ----
    for (int row = tid; row < 304; row += 256) {
        int p = seg0 - 21 + row;
        float acc[8];
#pragma unroll
        for (int c = 0; c < 8; ++c) acc[c] = 0.0f;
        if (p >= 0 && p < OL) {
            int imin = (p >= PT) ? (p - (PT - PSTRIDE)) / PSTRIDE : 0;
            int imax = p / PSTRIDE; if (imax > NP - 1) imax = NP - 1;
            float wsum = 0.0f;
            for (int i = imin; i <= imax; ++i) {
                int t = p - i * PSTRIDE;
                float w = (t < 50) ? t * (1.0f / 49.0f)
                                   : ((t >= 150) ? (199 - t) * (1.0f / 49.0f) : 1.0f);
                wsum += w;
                const unsigned short* pp = pat + ((size_t)(b * NP + i) * NC) * PT + t;
#pragma unroll
                for (int c = 0; c < 8; ++c) acc[c] += bf2f(pp[c * PT]) * w;
            }
            float inv = 1.0f / fmaxf(wsum, 1e-8f);
#pragma unroll
            for (int c = 0; c < 8; ++c) acc[c] *= inv;
        }
        ushort4 o0, o1;
        o0.x = f2bf(acc[0]); o0.y = f2bf(acc[1]); o0.z = f2bf(acc[2]); o0.w = f2bf(acc[3]);
        o1.x = f2bf(acc[4]); o1.y = f2bf(acc[5]); o1.z = f2bf(acc[6]); o1.w = f2bf(acc[7]);
        *(ushort4*)(xs + row * 8)     = o0;
        *(ushort4*)(xs + row * 8 + 4) = o1;
        int cr = row - 21;
        if (cr >= 0 && cr < 256) {
            float4 v0 = { acc[0], acc[1], acc[2], acc[3] };
            float4 v1 = { acc[4], acc[5], acc[6], acc[7] };
            *(float4*)(r2 + cr * 12)     = v0;
            *(float4*)(r2 + cr * 12 + 4) = v1;
        }
    }
    __syncthreads();

    // ---- conv1: 8 -> 32, k15, gelu -> ys1 (288 positions) ----
    {
        bf16x8 wf[4][2];
#pragma unroll
        for (int kb = 0; kb < 4; ++kb)
#pragma unroll
            for (int ot = 0; ot < 2; ++ot)
                wf[kb][ot] = *(const bf16x8*)(Wt1 + (kb * 32 + ot * 16 + l15) * 32 + quad * 8);
#pragma unroll
        for (int u = 0; u < 5; ++u) {
            const int base = wid * 80 + u * 16;
            if (base < 288) {
                const int posl = base + l15;
                floatx4 a0 = (floatx4)0.0f, a1 = (floatx4)0.0f;
#pragma unroll
                for (int kb = 0; kb < 4; ++kb) {
                    int row = posl + kb * 4 + quad;
                    bf16x8 bfrag = *(const bf16x8*)(xs + row * 8);
                    a0 = __builtin_amdgcn_mfma_f32_16x16x32_bf16(wf[kb][0], bfrag, a0, 0, 0, 0);
                    a1 = __builtin_amdgcn_mfma_f32_16x16x32_bf16(wf[kb][1], bfrag, a1, 0, 0, 0);
                }
                int oc0 = quad * 4;
                ushort4 o;
                o.x = f2bf(gelu_erf(a0[0] + bs1[oc0]));
                o.y = f2bf(gelu_erf(a0[1] + bs1[oc0 + 1]));
                o.z = f2bf(gelu_erf(a0[2] + bs1[oc0 + 2]));
                o.w = f2bf(gelu_erf(a0[3] + bs1[oc0 + 3]));
                *(ushort4*)(ys1 + posl * 40 + oc0) = o;
                int oc1 = 16 + quad * 4;
                o.x = f2bf(gelu_erf(a1[0] + bs1[oc1]));
                o.y = f2bf(gelu_erf(a1[1] + bs1[oc1 + 1]));
                o.z = f2bf(gelu_erf(a1[2] + bs1[oc1 + 2]));
                o.w = f2bf(gelu_erf(a1[3] + bs1[oc1 + 3]));
                *(ushort4*)(ys1 + posl * 40 + oc1) = o;
            }
        }
    }
    __syncthreads();

    // ---- conv2: 32 -> 16, k15, gelu -> ys2 (272 positions) ----
    {
        bf16x8 wf[15];
#pragma unroll
        for (int t = 0; t < 15; ++t)
            wf[t] = *(const bf16x8*)(Wt2 + (t * 16 + l15) * 32 + quad * 8);
#pragma unroll
        for (int u = 0; u < 5; ++u) {
            const int base = wid * 80 + u * 16;
            if (base < 272) {
                const int posl = base + l15;
                floatx4 a = (floatx4)0.0f;
#pragma unroll
                for (int t = 0; t < 15; ++t) {
                    bf16x8 bfrag = *(const bf16x8*)(ys1 + (posl + t) * 40 + quad * 8);
                    a = __builtin_amdgcn_mfma_f32_16x16x32_bf16(wf[t], bfrag, a, 0, 0, 0);
                }
                int oc0 = quad * 4;
                ushort4 o;
                o.x = f2bf(gelu_erf(a[0] + bs2[oc0]));
                o.y = f2bf(gelu_erf(a[1] + bs2[oc0 + 1]));
                o.z = f2bf(gelu_erf(a[2] + bs2[oc0 + 2]));
                o.w = f2bf(gelu_erf(a[3] + bs2[oc0 + 3]));
                *(ushort4*)(ys2 + posl * 24 + oc0) = o;
            }
        }
    }
    __syncthreads();

    // ---- conv3: 16 -> 8, k15, + residual (into r2) ----
    {
        bf16x8 wf[8];
#pragma unroll
        for (int kb = 0; kb < 8; ++kb)
            wf[kb] = *(const bf16x8*)(Wt3 + (kb * 16 + l15) * 32 + quad * 8);
#pragma unroll
        for (int u = 0; u < 5; ++u) {
            const int base = wid * 80 + u * 16;
            if (base < 256) {
                const int posl = base + l15;
                floatx4 a = (floatx4)0.0f;
#pragma unroll
                for (int kb = 0; kb < 8; ++kb) {
                    int row = posl + kb * 2 + (quad >> 1);
                    bf16x8 bfrag = *(const bf16x8*)(ys2 + row * 24 + (quad & 1) * 8);
                    a = __builtin_amdgcn_mfma_f32_16x16x32_bf16(wf[kb], bfrag, a, 0, 0, 0);
                }
                if (quad < 2) {
                    int oc0 = quad * 4;
                    float4 rv = *(const float4*)(r2 + posl * 12 + oc0);
                    rv.x += a[0] + bs3[oc0];
                    rv.y += a[1] + bs3[oc0 + 1];
                    rv.z += a[2] + bs3[oc0 + 2];
                    rv.w += a[3] + bs3[oc0 + 3];
                    *(float4*)(r2 + posl * 12 + oc0) = rv;
                }
            }
        }
    }
    __syncthreads();

    // ---- pointwise 8x8 + store ----
    {
        int p = seg0 + tid;
        if (p < OL) {
            float4 a = *(const float4*)(r2 + tid * 12);
            float4 c = *(const float4*)(r2 + tid * 12 + 4);
#pragma unroll
            for (int o = 0; o < 8; ++o) {
                float v = bsp[o];
                v += pws[o * 8 + 0] * a.x + pws[o * 8 + 1] * a.y + pws[o * 8 + 2] * a.z + pws[o * 8 + 3] * a.w;
                v += pws[o * 8 + 4] * c.x + pws[o * 8 + 5] * c.y + pws[o * 8 + 6] * c.z + pws[o * 8 + 7] * c.w;
                out[((size_t)b * 8 + o) * OL + p] = v;
            }
        }
    }
}

// ---------------------------------------------------------------------------
extern "C" void kernel_launch(void* const* d_in, const int* in_sizes, int n_in,
                              void* d_out, int out_size, void* d_ws, size_t ws_size,
                              hipStream_t stream) {
    const float* X   = (const float*)d_in[0];
    const float* W1  = (const float*)d_in[1];
    const float* b1  = (const float*)d_in[2];
    const float* W2  = (const float*)d_in[3];
    const float* b2  = (const float*)d_in[4];
    const float* rw1 = (const float*)d_in[5];
    const float* rb1 = (const float*)d_in[6];
    const float* rw2 = (const float*)d_in[7];
    const float* rb2 = (const float*)d_in[8];
    const float* rw3 = (const float*)d_in[9];
    const float* rb3 = (const float*)d_in[10];
    const float* pw  = (const float*)d_in[11];
    const float* pb  = (const float*)d_in[12];
    float* out = (float*)d_out;

    char* ws = (char*)d_ws;
    unsigned short* W1t = (unsigned short*)(ws +  92274688);   //     524,288
    unsigned short* W2t = (unsigned short*)(ws +  92798976);   //     262,144
    unsigned short* h   = (unsigned short*)(ws +  93061120);   //  92,274,688
    unsigned short* pat = (unsigned short*)(ws + 185335808);   //  36,044,800 (bf16 patches)
    unsigned short* Wt1 = (unsigned short*)(ws + 322961408);   //       8,192
    unsigned short* Wt2 = (unsigned short*)(ws + 322969600);   //      15,360
    unsigned short* Wt3 = (unsigned short*)(ws + 322984960);   //       8,192

    prep_w_kernel<<<1536, 256, 0, stream>>>(W1, W2, W1t, W2t);
    prep_cw_kernel<<<62, 256, 0, stream>>>(rw1, rw2, rw3, Wt1, Wt2, Wt3);
    // gemm1 reads X (fp32) directly; cast fused into A-staging
    gemm_lds_kernel<true,  true,  true, 2><<<2816, 256, 0, stream>>>((const void*)X, W1t, b1, (void*)h,   512, 512);
    gemm_lds_kernel<false, false, true, 1><<<1408, 256, 0, stream>>>((const void*)h,  W2t, b2, (void*)pat, 200, 200);
    tail_fused<<<dim3(8, NB), 256, 0, stream>>>(pat, Wt1, rb1, Wt2, rb2, Wt3, rb3, pw, pb, out);
}